// Round 8
// baseline (299.483 us; speedup 1.0000x reference)
//
#include <hip/hip_runtime.h>
#include <hip/hip_bf16.h>

#define N_NODES 50000
#define N_EDGES 800000
#define HEADS 8
#define HID 16
#define HC 128  // HEADS*HID

typedef __attribute__((ext_vector_type(8))) short bf16x8;
typedef __attribute__((ext_vector_type(4))) float f32x4;
typedef __attribute__((ext_vector_type(2))) float f32x2;
typedef __attribute__((ext_vector_type(4))) int i32x4;

__device__ __forceinline__ float bf2f(unsigned short u) {
  union { unsigned int i; float f; } v;
  v.i = (unsigned int)u << 16;
  return v.f;
}
__device__ __forceinline__ unsigned short f2bf(float f) {
  __hip_bfloat16 h = __float2bfloat16(f);
  return *(unsigned short*)&h;
}

// DPP-based add of lane (this ^ pattern) -- pure VALU, replaces ds_swizzle shfl.
// 0xB1 = quad_perm [1,0,3,2] (xor1), 0x4E = quad_perm [2,3,0,1] (xor2),
// 0x141 = row_half_mirror (xor-ish over 8-lane group; valid for sums).
template <int CTRL>
__device__ __forceinline__ float dpp_addf(float x) {
  const int r = __builtin_amdgcn_update_dpp(0, __float_as_int(x), CTRL, 0xF, 0xF, true);
  return x + __int_as_float(r);
}

// ---------------------------------------------------------------------------
// K1: prep = [blocks 0..3124] degree histogram  U  [3125..3252] W transpose.
// ---------------------------------------------------------------------------
__global__ __launch_bounds__(256) void k_prep(
    const int* __restrict__ eidx, const float* __restrict__ Wl,
    const float* __restrict__ Wr, int* __restrict__ deg,
    unsigned short* __restrict__ WcatT) {
  const int b = blockIdx.x;
  if (b < 3125) {
    const int e = b * 256 + threadIdx.x;  // 800000 exact
    const int d = __builtin_nontemporal_load(eidx + N_EDGES + e);
    atomicAdd(&deg[d], 1);
  } else {
    const int idx = (b - 3125) * 256 + threadIdx.x;  // < 32768
    const int n = idx >> 7, k = idx & 127;
    const float* W = (n < 128) ? Wl : Wr;
    WcatT[idx] = f2bf(W[k * HC + (n & 127)]);
  }
}

// ---------------------------------------------------------------------------
// K2: [blocks 0..390] MFMA GEMM: x(fp32 -> bf16 in staging) @ [Wl|Wr]
//     [blocks 391..488] CSR region allocation (wave prefix-scan + atomic).
// ---------------------------------------------------------------------------
__global__ __launch_bounds__(512) void k_gemm_alloc(
    const float* __restrict__ x, const unsigned short* __restrict__ WcatT,
    const float* __restrict__ bl, const float* __restrict__ br,
    unsigned short* __restrict__ xl, unsigned short* __restrict__ xr,
    const int* __restrict__ deg, int* __restrict__ counter,
    int* __restrict__ offs) {
  __shared__ unsigned short As[128 * 136];  // pad 8 shorts: bank spread
  const int t = threadIdx.x;

  if (blockIdx.x >= 391) {  // ---- CSR alloc part ----
    const int node = (blockIdx.x - 391) * 512 + t;  // 98*512 = 50176
    const int lane = t & 63;
    const int v = (node < N_NODES) ? deg[node] : 0;
    int incl = v;
#pragma unroll
    for (int d = 1; d < 64; d <<= 1) {
      const int tt = __shfl_up(incl, d);
      if (lane >= d) incl += tt;
    }
    const int total = __shfl(incl, 63);
    int base = 0;
    if (lane == 63) base = atomicAdd(counter, total);
    base = __shfl(base, 63);
    if (node < N_NODES) offs[node] = base + incl - v;
    return;
  }

  // ---- GEMM part ----
  const int m0 = blockIdx.x * 128;
#pragma unroll
  for (int it = 0; it < 4; ++it) {
    const int c = t + it * 512;
    const int row = c >> 4;
    const int seg = (c & 15) * 8;
    const int grow = m0 + row;
    float4 a = make_float4(0.f, 0.f, 0.f, 0.f), bb2 = a;
    if (grow < N_NODES) {
      const float4* p = (const float4*)(x + (size_t)grow * 128 + seg);
      a = p[0];
      bb2 = p[1];
    }
    union { unsigned short s[8]; uint4 v; } o;
    o.s[0] = f2bf(a.x);   o.s[1] = f2bf(a.y);
    o.s[2] = f2bf(a.z);   o.s[3] = f2bf(a.w);
    o.s[4] = f2bf(bb2.x); o.s[5] = f2bf(bb2.y);
    o.s[6] = f2bf(bb2.z); o.s[7] = f2bf(bb2.w);
    *(uint4*)(&As[row * 136 + seg]) = o.v;
  }
  __syncthreads();

  const int w = t >> 6, lane = t & 63;
  const int wm = w >> 2, wn = w & 3;
  const int lr = lane & 15, lk = lane >> 4;

  f32x4 acc[4][4];
#pragma unroll
  for (int i = 0; i < 4; ++i)
#pragma unroll
    for (int j = 0; j < 4; ++j) acc[i][j] = (f32x4)(0.f);

  const unsigned short* Wbase = WcatT + (size_t)(wn * 64 + lr) * 128;
#pragma unroll
  for (int ks = 0; ks < 4; ++ks) {
    const int k = ks * 32 + lk * 8;
    bf16x8 bfr[4], afr[4];
#pragma unroll
    for (int ni = 0; ni < 4; ++ni)
      bfr[ni] = *(const bf16x8*)(Wbase + ni * 16 * 128 + k);
#pragma unroll
    for (int mi = 0; mi < 4; ++mi)
      afr[mi] = *(const bf16x8*)(&As[(wm * 64 + mi * 16 + lr) * 136 + k]);
#pragma unroll
    for (int mi = 0; mi < 4; ++mi)
#pragma unroll
      for (int ni = 0; ni < 4; ++ni)
        acc[mi][ni] = __builtin_amdgcn_mfma_f32_16x16x32_bf16(
            afr[mi], bfr[ni], acc[mi][ni], 0, 0, 0);
  }

#pragma unroll
  for (int ni = 0; ni < 4; ++ni) {
    const int gcol = wn * 64 + ni * 16 + lr;  // 0..255
    const bool left = gcol < 128;
    const float bb = left ? bl[gcol] : br[gcol - 128];
    unsigned short* __restrict__ dst = left ? xl : xr;
    const int cc = gcol & 127;
#pragma unroll
    for (int mi = 0; mi < 4; ++mi) {
#pragma unroll
      for (int r = 0; r < 4; ++r) {
        const int grow = m0 + wm * 64 + mi * 16 + lk * 4 + r;
        if (grow < N_NODES) dst[(size_t)grow * HC + cc] = f2bf(acc[mi][ni][r] + bb);
      }
    }
  }
}

// ---------------------------------------------------------------------------
// K3: scatter packed edge records {src, ea.x, ea.y, 0} into CSR order.
// Stream-once data uses nontemporal access to keep L2 clean.
// ---------------------------------------------------------------------------
__global__ __launch_bounds__(256) void k_scatter(
    const int* __restrict__ eidx, const float* __restrict__ eattr,
    const int* __restrict__ offs, int* __restrict__ cursor,
    i32x4* __restrict__ epack) {
  const int e = blockIdx.x * 256 + threadIdx.x;  // 800000 exact
  const int src = __builtin_nontemporal_load(eidx + e);
  const int d = __builtin_nontemporal_load(eidx + N_EDGES + e);
  const f32x2 ea = __builtin_nontemporal_load((const f32x2*)eattr + e);
  const int pos = atomicAdd(&cursor[d], 1);
  i32x4 rec;
  rec.x = src;
  rec.y = __float_as_int(ea.x);
  rec.z = __float_as_int(ea.y);
  rec.w = 0;
  __builtin_nontemporal_store(rec, epack + offs[d] + pos);
}

// ---------------------------------------------------------------------------
// K4: merged attention + aggregation + BN partial stats.
// One wave per node; lane owns channels (2*lane, 2*lane+1), head = lane>>3.
// Full batches of 4 edges run guard-free with 2-stage prefetch; logit reduce
// via DPP (VALU-only). epack/xr nontemporal; xl gathers cached (hot set).
// ---------------------------------------------------------------------------
#define LOADB(EP, K)                                   \
  _Pragma("unroll") for (int j = 0; j < 4; ++j) EP[j] = \
      __builtin_nontemporal_load(epack + (K) + j);
#define LOADX(XW, EP)                                                        \
  _Pragma("unroll") for (int j = 0; j < 4; ++j)                              \
      XW[j] = *(const unsigned int*)((const char*)xl +                       \
              (((unsigned)EP[j].x << 8) + lb));
#define EDGE1(EPJ, XWJ)                                                     \
  {                                                                         \
    const float eax = __int_as_float((EPJ).y);                              \
    const float eay = __int_as_float((EPJ).z);                              \
    const float x0 = bf2f((unsigned short)(XWJ));                           \
    const float x1 = bf2f((unsigned short)((XWJ) >> 16));                   \
    float m0 = fmaf(eax, w0a, fmaf(eay, w1a, ca)) + x0;                     \
    float m1 = fmaf(eax, w0b, fmaf(eay, w1b, cb)) + x1;                     \
    m0 = fmaxf(m0, 0.2f * m0);                                              \
    m1 = fmaxf(m1, 0.2f * m1);                                              \
    float p = fmaf(m0, ata, m1 * atb);                                      \
    p = dpp_addf<0xB1>(p);                                                  \
    p = dpp_addf<0x4E>(p);                                                  \
    p = dpp_addf<0x141>(p);                                                 \
    const float exv = __expf(p);                                            \
    dn += exv;                                                              \
    a0 = fmaf(exv, x0, a0);                                                 \
    a1 = fmaf(exv, x1, a1);                                                 \
  }
#define COMPUTE4(EP, XW)                               \
  _Pragma("unroll") for (int j = 0; j < 4; ++j) EDGE1(EP[j], XW[j])

__global__ __launch_bounds__(256) void k_attagg(
    const int* __restrict__ offs, const int* __restrict__ deg,
    const i32x4* __restrict__ epack,
    const unsigned short* __restrict__ xl, const unsigned short* __restrict__ xr,
    const float* __restrict__ We, const float* __restrict__ be,
    const float* __restrict__ att, float* __restrict__ outp,
    float* __restrict__ statsB) {
  __shared__ float ssum[4 * 128];
  __shared__ float ssq[4 * 128];
  const int wave = threadIdx.x >> 6, lane = threadIdx.x & 63;
  const int node = blockIdx.x * 4 + wave;  // 12500*4 = 50000 exact
  const int c0 = lane * 2;
  const unsigned lb = (unsigned)lane << 2;  // byte offset of lane's channel pair

  const float w0a = We[c0],      w0b = We[c0 + 1];
  const float w1a = We[HC + c0], w1b = We[HC + c0 + 1];
  const float ata = att[c0],     atb = att[c0 + 1];

  const unsigned int xrw =
      __builtin_nontemporal_load((const unsigned int*)(xr + (size_t)node * HC) + lane);
  const float ca = be[c0] + bf2f((unsigned short)xrw);
  const float cb = be[c0 + 1] + bf2f((unsigned short)(xrw >> 16));

  const int beg = offs[node];
  const int dn_e = deg[node];
  const int end = beg + dn_e;
  const int nf = dn_e >> 2;  // full batches of 4

  float dn = 0.f, a0 = 0.f, a1 = 0.f;

  if (nf >= 1) {
    i32x4 epA[4], epB[4];
    unsigned int xwA[4];
    LOADB(epA, beg)
    LOADX(xwA, epA)
    if (nf >= 2) LOADB(epB, beg + 4)
    for (int b = 0; b + 1 < nf; ++b) {
      unsigned int xwB[4];
      i32x4 epC[4];
      LOADX(xwB, epB)
      if (b + 2 < nf) LOADB(epC, beg + (b + 2) * 4)
      COMPUTE4(epA, xwA)
#pragma unroll
      for (int j = 0; j < 4; ++j) { epA[j] = epB[j]; xwA[j] = xwB[j]; epB[j] = epC[j]; }
    }
    COMPUTE4(epA, xwA)
  }
  for (int k = beg + (nf << 2); k < end; ++k) {  // <=3 tail edges
    const i32x4 ep = __builtin_nontemporal_load(epack + k);
    const unsigned int xw =
        *(const unsigned int*)((const char*)xl + (((unsigned)ep.x << 8) + lb));
    EDGE1(ep, xw)
  }

  const float inv = dn > 0.f ? 1.0f / dn : 0.f;
  const float o0 = a0 * inv, o1 = a1 * inv;
  f32x2 o;
  o.x = o0;
  o.y = o1;
  __builtin_nontemporal_store(o, (f32x2*)(outp + (size_t)node * HC) + lane);

  // BN partial stats: block LDS reduce, then 8-way replicated bucket atomics
  ssum[wave * 128 + c0]     = o0;
  ssum[wave * 128 + c0 + 1] = o1;
  ssq[wave * 128 + c0]      = o0 * o0;
  ssq[wave * 128 + c0 + 1]  = o1 * o1;
  __syncthreads();
  if (threadIdx.x < 128) {
    const int c = threadIdx.x;
    const float s1 = ssum[c] + ssum[128 + c] + ssum[256 + c] + ssum[384 + c];
    const float s2 = ssq[c] + ssq[128 + c] + ssq[256 + c] + ssq[384 + c];
    float* bkt = statsB + (blockIdx.x & 7) * 256;
    atomicAdd(&bkt[c], s1);
    atomicAdd(&bkt[128 + c], s2);
  }
}

// ---------------------------------------------------------------------------
// K5: BatchNorm + LeakyReLU(0.01). Each block: reduce the 8 stat buckets,
// then normalize 1024 consecutive floats (float4).
// ---------------------------------------------------------------------------
__global__ __launch_bounds__(256) void k_bn(const float* __restrict__ statsB,
                                            const float* __restrict__ gamma,
                                            const float* __restrict__ beta,
                                            float* __restrict__ outp) {
  __shared__ float sscale[128], sshift[128];
  const int t = threadIdx.x;
  if (t < 128) {
    float s1 = 0.f, s2 = 0.f;
#pragma unroll
    for (int b = 0; b < 8; ++b) {
      s1 += statsB[b * 256 + t];
      s2 += statsB[b * 256 + 128 + t];
    }
    const float mean = s1 * (1.0f / N_NODES);
    const float var = s2 * (1.0f / N_NODES) - mean * mean;
    const float rstd = rsqrtf(var + 1e-5f);
    const float sc = rstd * gamma[t];
    sscale[t] = sc;
    sshift[t] = beta[t] - mean * sc;
  }
  __syncthreads();
  const size_t base = (size_t)blockIdx.x * 1024 + t * 4;  // 6250*1024 = 6.4M exact
  float4 v = *(const float4*)(outp + base);
  const int c = (t * 4) & 127;
  v.x = fmaf(v.x, sscale[c],     sshift[c]);
  v.y = fmaf(v.y, sscale[c + 1], sshift[c + 1]);
  v.z = fmaf(v.z, sscale[c + 2], sshift[c + 2]);
  v.w = fmaf(v.w, sscale[c + 3], sshift[c + 3]);
  v.x = fmaxf(v.x, 0.01f * v.x);
  v.y = fmaxf(v.y, 0.01f * v.y);
  v.z = fmaxf(v.z, 0.01f * v.z);
  v.w = fmaxf(v.w, 0.01f * v.w);
  *(float4*)(outp + base) = v;
}

// ---------------------------------------------------------------------------
extern "C" void kernel_launch(void* const* d_in, const int* in_sizes, int n_in,
                              void* d_out, int out_size, void* d_ws, size_t ws_size,
                              hipStream_t stream) {
  const float* x     = (const float*)d_in[0];
  const int*   eidx  = (const int*)d_in[1];
  const float* eattr = (const float*)d_in[2];
  const float* Wl    = (const float*)d_in[3];
  const float* bl    = (const float*)d_in[4];
  const float* Wr    = (const float*)d_in[5];
  const float* br    = (const float*)d_in[6];
  const float* We    = (const float*)d_in[7];
  const float* be    = (const float*)d_in[8];
  const float* att   = (const float*)d_in[9];
  // d_in[10] = bias: cancels exactly in BatchNorm mean subtraction -> unused
  const float* gamma = (const float*)d_in[11];
  const float* beta  = (const float*)d_in[12];
  float* out = (float*)d_out;

  char* ws = (char*)d_ws;
  size_t off = 0;
  auto alloc = [&](size_t bytes) {
    size_t o = off;
    off = (off + bytes + 15) & ~size_t(15);
    return o;
  };
  // zero-initialized region first
  const size_t o_deg   = alloc((size_t)(N_NODES + 1) * 4);
  const size_t o_cur   = alloc((size_t)N_NODES * 4);
  const size_t o_cnt   = alloc(16);
  const size_t o_stats = alloc((size_t)8 * 256 * 4);
  const size_t zero_bytes = off;
  // non-zeroed scratch
  const size_t o_offs = alloc((size_t)(N_NODES + 1) * 4);
  const size_t o_ep   = alloc((size_t)N_EDGES * 16);
  const size_t o_wt   = alloc((size_t)256 * 128 * 2);
  const size_t o_xl   = alloc((size_t)N_NODES * HC * 2);
  const size_t o_xr   = alloc((size_t)N_NODES * HC * 2);
  (void)ws_size; (void)in_sizes; (void)n_in; (void)out_size;

  int*   deg    = (int*)(ws + o_deg);
  int*   cur    = (int*)(ws + o_cur);
  int*   cnt    = (int*)(ws + o_cnt);
  float* statsB = (float*)(ws + o_stats);
  int*   offs   = (int*)(ws + o_offs);
  i32x4* epack  = (i32x4*)(ws + o_ep);
  unsigned short* WcatT = (unsigned short*)(ws + o_wt);
  unsigned short* xl    = (unsigned short*)(ws + o_xl);
  unsigned short* xr    = (unsigned short*)(ws + o_xr);

  hipMemsetAsync(ws, 0, zero_bytes, stream);

  k_prep<<<3253, 256, 0, stream>>>(eidx, Wl, Wr, deg, WcatT);
  k_gemm_alloc<<<489, 512, 0, stream>>>(x, WcatT, bl, br, xl, xr, deg, cnt, offs);
  k_scatter<<<3125, 256, 0, stream>>>(eidx, eattr, offs, cur, epack);
  k_attagg<<<12500, 256, 0, stream>>>(offs, deg, epack, xl, xr, We, be, att, out,
                                      statsB);
  k_bn<<<6250, 256, 0, stream>>>(statsB, gamma, beta, out);
}

// Round 10
// 289.758 us; speedup vs baseline: 1.0336x; 1.0336x over previous
//
#include <hip/hip_runtime.h>
#include <hip/hip_bf16.h>

#define N_NODES 50000
#define N_EDGES 800000
#define HEADS 8
#define HID 16
#define HC 128  // HEADS*HID

typedef __attribute__((ext_vector_type(8))) short bf16x8;
typedef __attribute__((ext_vector_type(4))) float f32x4;
typedef __attribute__((ext_vector_type(2))) float f32x2;
typedef __attribute__((ext_vector_type(2))) int i32x2;

__device__ __forceinline__ float bf2f(unsigned short u) {
  union { unsigned int i; float f; } v;
  v.i = (unsigned int)u << 16;
  return v.f;
}
__device__ __forceinline__ unsigned short f2bf(float f) {
  __hip_bfloat16 h = __float2bfloat16(f);
  return *(unsigned short*)&h;
}

// DPP-based 8-lane-group sum (xor1, xor2, half-mirror) -- pure VALU.
template <int CTRL>
__device__ __forceinline__ float dpp_addf(float x) {
  const int r = __builtin_amdgcn_update_dpp(0, __float_as_int(x), CTRL, 0xF, 0xF, true);
  return x + __int_as_float(r);
}

// ---------------------------------------------------------------------------
// K1: prep = [blocks 0..3124] degree histogram  U  [3125..3252] W transpose.
// ---------------------------------------------------------------------------
__global__ __launch_bounds__(256) void k_prep(
    const int* __restrict__ eidx, const float* __restrict__ Wl,
    const float* __restrict__ Wr, int* __restrict__ deg,
    unsigned short* __restrict__ WcatT) {
  const int b = blockIdx.x;
  if (b < 3125) {
    const int e = b * 256 + threadIdx.x;  // 800000 exact
    const int d = __builtin_nontemporal_load(eidx + N_EDGES + e);
    atomicAdd(&deg[d], 1);
  } else {
    const int idx = (b - 3125) * 256 + threadIdx.x;  // < 32768
    const int n = idx >> 7, k = idx & 127;
    const float* W = (n < 128) ? Wl : Wr;
    WcatT[idx] = f2bf(W[k * HC + (n & 127)]);
  }
}

// ---------------------------------------------------------------------------
// K2: [blocks 0..390] MFMA GEMM: x(fp32 -> bf16 in staging) @ [Wl|Wr]
//     [blocks 391..488] CSR region allocation (wave prefix-scan + atomic).
// ---------------------------------------------------------------------------
__global__ __launch_bounds__(512) void k_gemm_alloc(
    const float* __restrict__ x, const unsigned short* __restrict__ WcatT,
    const float* __restrict__ bl, const float* __restrict__ br,
    unsigned short* __restrict__ xl, unsigned short* __restrict__ xr,
    const int* __restrict__ deg, int* __restrict__ counter,
    int* __restrict__ offs) {
  __shared__ unsigned short As[128 * 136];  // pad 8 shorts: bank spread
  const int t = threadIdx.x;

  if (blockIdx.x >= 391) {  // ---- CSR alloc part ----
    const int node = (blockIdx.x - 391) * 512 + t;  // 98*512 = 50176
    const int lane = t & 63;
    const int v = (node < N_NODES) ? deg[node] : 0;
    int incl = v;
#pragma unroll
    for (int d = 1; d < 64; d <<= 1) {
      const int tt = __shfl_up(incl, d);
      if (lane >= d) incl += tt;
    }
    const int total = __shfl(incl, 63);
    int base = 0;
    if (lane == 63) base = atomicAdd(counter, total);
    base = __shfl(base, 63);
    if (node < N_NODES) offs[node] = base + incl - v;
    return;
  }

  // ---- GEMM part ----
  const int m0 = blockIdx.x * 128;
#pragma unroll
  for (int it = 0; it < 4; ++it) {
    const int c = t + it * 512;
    const int row = c >> 4;
    const int seg = (c & 15) * 8;
    const int grow = m0 + row;
    float4 a = make_float4(0.f, 0.f, 0.f, 0.f), bb2 = a;
    if (grow < N_NODES) {
      const float4* p = (const float4*)(x + (size_t)grow * 128 + seg);
      a = p[0];
      bb2 = p[1];
    }
    union { unsigned short s[8]; uint4 v; } o;
    o.s[0] = f2bf(a.x);   o.s[1] = f2bf(a.y);
    o.s[2] = f2bf(a.z);   o.s[3] = f2bf(a.w);
    o.s[4] = f2bf(bb2.x); o.s[5] = f2bf(bb2.y);
    o.s[6] = f2bf(bb2.z); o.s[7] = f2bf(bb2.w);
    *(uint4*)(&As[row * 136 + seg]) = o.v;
  }
  __syncthreads();

  const int w = t >> 6, lane = t & 63;
  const int wm = w >> 2, wn = w & 3;
  const int lr = lane & 15, lk = lane >> 4;

  f32x4 acc[4][4];
#pragma unroll
  for (int i = 0; i < 4; ++i)
#pragma unroll
    for (int j = 0; j < 4; ++j) acc[i][j] = (f32x4)(0.f);

  const unsigned short* Wbase = WcatT + (size_t)(wn * 64 + lr) * 128;
#pragma unroll
  for (int ks = 0; ks < 4; ++ks) {
    const int k = ks * 32 + lk * 8;
    bf16x8 bfr[4], afr[4];
#pragma unroll
    for (int ni = 0; ni < 4; ++ni)
      bfr[ni] = *(const bf16x8*)(Wbase + ni * 16 * 128 + k);
#pragma unroll
    for (int mi = 0; mi < 4; ++mi)
      afr[mi] = *(const bf16x8*)(&As[(wm * 64 + mi * 16 + lr) * 136 + k]);
#pragma unroll
    for (int mi = 0; mi < 4; ++mi)
#pragma unroll
      for (int ni = 0; ni < 4; ++ni)
        acc[mi][ni] = __builtin_amdgcn_mfma_f32_16x16x32_bf16(
            afr[mi], bfr[ni], acc[mi][ni], 0, 0, 0);
  }

#pragma unroll
  for (int ni = 0; ni < 4; ++ni) {
    const int gcol = wn * 64 + ni * 16 + lr;  // 0..255
    const bool left = gcol < 128;
    const float bb = left ? bl[gcol] : br[gcol - 128];
    unsigned short* __restrict__ dst = left ? xl : xr;
    const int cc = gcol & 127;
#pragma unroll
    for (int mi = 0; mi < 4; ++mi) {
#pragma unroll
      for (int r = 0; r < 4; ++r) {
        const int grow = m0 + wm * 64 + mi * 16 + lk * 4 + r;
        if (grow < N_NODES) dst[(size_t)grow * HC + cc] = f2bf(acc[mi][ni][r] + bb);
      }
    }
  }
}

// ---------------------------------------------------------------------------
// K3: scatter packed 8B edge records {src, bf16(ea.x)|bf16(ea.y)<<16} into
// CSR order. Stream-once data -> nontemporal.
// ---------------------------------------------------------------------------
__global__ __launch_bounds__(256) void k_scatter(
    const int* __restrict__ eidx, const float* __restrict__ eattr,
    const int* __restrict__ offs, int* __restrict__ cursor,
    i32x2* __restrict__ epack) {
  const int e = blockIdx.x * 256 + threadIdx.x;  // 800000 exact
  const int src = __builtin_nontemporal_load(eidx + e);
  const int d = __builtin_nontemporal_load(eidx + N_EDGES + e);
  const f32x2 ea = __builtin_nontemporal_load((const f32x2*)eattr + e);
  const int pos = atomicAdd(&cursor[d], 1);
  i32x2 rec;
  rec.x = src;
  rec.y = (int)((unsigned)f2bf(ea.x) | ((unsigned)f2bf(ea.y) << 16));
  __builtin_nontemporal_store(rec, epack + offs[d] + pos);
}

// ---------------------------------------------------------------------------
// K4: merged attention + aggregation + BN partial stats.
// One wave per node; lane owns channels (2*lane, 2*lane+1), head = lane>>3.
// 3-deep software pipeline: while computing batch b, xl-rows of b+1 (arrived)
// and b+2 (in flight) + epack of b+3 are outstanding (~8 gathers/wave).
// att pre-scaled by log2(e) -> exp2f (one fewer dependent op).
// ---------------------------------------------------------------------------
#define LOADB(EP, K)                                   \
  _Pragma("unroll") for (int j = 0; j < 4; ++j) EP[j] = \
      __builtin_nontemporal_load(epack + (K) + j);
#define LOADX(XW, EP)                                                        \
  _Pragma("unroll") for (int j = 0; j < 4; ++j)                              \
      XW[j] = *(const unsigned int*)((const char*)xl +                       \
              (((unsigned)EP[j].x << 8) + lb));
#define EDGE1(EPJ, XWJ)                                                     \
  {                                                                         \
    const unsigned eu = (unsigned)(EPJ).y;                                  \
    const float eax = bf2f((unsigned short)eu);                             \
    const float eay = bf2f((unsigned short)(eu >> 16));                     \
    const float x0 = bf2f((unsigned short)(XWJ));                           \
    const float x1 = bf2f((unsigned short)((XWJ) >> 16));                   \
    float m0 = fmaf(eax, w0a, fmaf(eay, w1a, ca)) + x0;                     \
    float m1 = fmaf(eax, w0b, fmaf(eay, w1b, cb)) + x1;                     \
    m0 = fmaxf(m0, 0.2f * m0);                                              \
    m1 = fmaxf(m1, 0.2f * m1);                                              \
    float p = fmaf(m0, ata, m1 * atb);                                      \
    p = dpp_addf<0xB1>(p);                                                  \
    p = dpp_addf<0x4E>(p);                                                  \
    p = dpp_addf<0x141>(p);                                                 \
    const float exv = exp2f(p);                                             \
    dn += exv;                                                              \
    a0 = fmaf(exv, x0, a0);                                                 \
    a1 = fmaf(exv, x1, a1);                                                 \
  }
#define COMPUTE4(EP, XW)                               \
  _Pragma("unroll") for (int j = 0; j < 4; ++j) EDGE1(EP[j], XW[j])
#define SHIFT4(A, B)                                   \
  _Pragma("unroll") for (int j = 0; j < 4; ++j) A[j] = B[j];

__global__ __launch_bounds__(256) void k_attagg(
    const int* __restrict__ offs, const int* __restrict__ deg,
    const i32x2* __restrict__ epack,
    const unsigned short* __restrict__ xl, const unsigned short* __restrict__ xr,
    const float* __restrict__ We, const float* __restrict__ be,
    const float* __restrict__ att, float* __restrict__ outp,
    float* __restrict__ statsB) {
  __shared__ float ssum[4 * 128];
  __shared__ float ssq[4 * 128];
  const int wave = threadIdx.x >> 6, lane = threadIdx.x & 63;
  const int node = blockIdx.x * 4 + wave;  // 12500*4 = 50000 exact
  const int c0 = lane * 2;
  const unsigned lb = (unsigned)lane << 2;  // byte offset of lane's channel pair

  const float w0a = We[c0],      w0b = We[c0 + 1];
  const float w1a = We[HC + c0], w1b = We[HC + c0 + 1];
  const float LOG2E = 1.4426950408889634f;
  const float ata = att[c0] * LOG2E, atb = att[c0 + 1] * LOG2E;

  const unsigned int xrw =
      __builtin_nontemporal_load((const unsigned int*)(xr + (size_t)node * HC) + lane);
  const float ca = be[c0] + bf2f((unsigned short)xrw);
  const float cb = be[c0 + 1] + bf2f((unsigned short)(xrw >> 16));

  const int beg = offs[node];
  const int dn_e = deg[node];
  const int end = beg + dn_e;
  const int nf = dn_e >> 2;  // full batches of 4

  float dn = 0.f, a0 = 0.f, a1 = 0.f;

  if (nf >= 1) {
    i32x2 ep0[4], ep1[4], ep2[4];
    unsigned int xw0[4], xw1[4];
    LOADB(ep0, beg)
    if (nf >= 2) LOADB(ep1, beg + 4)
    if (nf >= 3) LOADB(ep2, beg + 8)
    LOADX(xw0, ep0)
    if (nf >= 2) LOADX(xw1, ep1)
    for (int b = 0; b + 2 < nf; ++b) {
      unsigned int xw2[4];
      i32x2 ep3[4];
      LOADX(xw2, ep2)                          // gathers for batch b+2
      if (b + 3 < nf) LOADB(ep3, beg + (b + 3) * 4)
      COMPUTE4(ep0, xw0)
      SHIFT4(ep0, ep1) SHIFT4(ep1, ep2) SHIFT4(ep2, ep3)
      SHIFT4(xw0, xw1) SHIFT4(xw1, xw2)
    }
    COMPUTE4(ep0, xw0)
    if (nf >= 2) COMPUTE4(ep1, xw1)
  }
  for (int k = beg + (nf << 2); k < end; ++k) {  // <=3 tail edges
    const i32x2 ep = __builtin_nontemporal_load(epack + k);
    const unsigned int xw =
        *(const unsigned int*)((const char*)xl + (((unsigned)ep.x << 8) + lb));
    EDGE1(ep, xw)
  }

  const float inv = dn > 0.f ? 1.0f / dn : 0.f;
  const float o0 = a0 * inv, o1 = a1 * inv;
  f32x2 o;
  o.x = o0;
  o.y = o1;
  __builtin_nontemporal_store(o, (f32x2*)(outp + (size_t)node * HC) + lane);

  // BN partial stats: block LDS reduce, then 8-way replicated bucket atomics
  ssum[wave * 128 + c0]     = o0;
  ssum[wave * 128 + c0 + 1] = o1;
  ssq[wave * 128 + c0]      = o0 * o0;
  ssq[wave * 128 + c0 + 1]  = o1 * o1;
  __syncthreads();
  if (threadIdx.x < 128) {
    const int c = threadIdx.x;
    const float s1 = ssum[c] + ssum[128 + c] + ssum[256 + c] + ssum[384 + c];
    const float s2 = ssq[c] + ssq[128 + c] + ssq[256 + c] + ssq[384 + c];
    float* bkt = statsB + (blockIdx.x & 7) * 256;
    atomicAdd(&bkt[c], s1);
    atomicAdd(&bkt[128 + c], s2);
  }
}

// ---------------------------------------------------------------------------
// K5: BatchNorm + LeakyReLU(0.01). Each block: reduce the 8 stat buckets,
// then normalize 1024 consecutive floats (f32x4, nontemporal).
// ---------------------------------------------------------------------------
__global__ __launch_bounds__(256) void k_bn(const float* __restrict__ statsB,
                                            const float* __restrict__ gamma,
                                            const float* __restrict__ beta,
                                            float* __restrict__ outp) {
  __shared__ float sscale[128], sshift[128];
  const int t = threadIdx.x;
  if (t < 128) {
    float s1 = 0.f, s2 = 0.f;
#pragma unroll
    for (int b = 0; b < 8; ++b) {
      s1 += statsB[b * 256 + t];
      s2 += statsB[b * 256 + 128 + t];
    }
    const float mean = s1 * (1.0f / N_NODES);
    const float var = s2 * (1.0f / N_NODES) - mean * mean;
    const float rstd = rsqrtf(var + 1e-5f);
    const float sc = rstd * gamma[t];
    sscale[t] = sc;
    sshift[t] = beta[t] - mean * sc;
  }
  __syncthreads();
  const size_t base = (size_t)blockIdx.x * 1024 + t * 4;  // 6250*1024 = 6.4M exact
  f32x4 v = __builtin_nontemporal_load((const f32x4*)(outp + base));
  const int c = (t * 4) & 127;
  v.x = fmaf(v.x, sscale[c],     sshift[c]);
  v.y = fmaf(v.y, sscale[c + 1], sshift[c + 1]);
  v.z = fmaf(v.z, sscale[c + 2], sshift[c + 2]);
  v.w = fmaf(v.w, sscale[c + 3], sshift[c + 3]);
  v.x = fmaxf(v.x, 0.01f * v.x);
  v.y = fmaxf(v.y, 0.01f * v.y);
  v.z = fmaxf(v.z, 0.01f * v.z);
  v.w = fmaxf(v.w, 0.01f * v.w);
  __builtin_nontemporal_store(v, (f32x4*)(outp + base));
}

// ---------------------------------------------------------------------------
extern "C" void kernel_launch(void* const* d_in, const int* in_sizes, int n_in,
                              void* d_out, int out_size, void* d_ws, size_t ws_size,
                              hipStream_t stream) {
  const float* x     = (const float*)d_in[0];
  const int*   eidx  = (const int*)d_in[1];
  const float* eattr = (const float*)d_in[2];
  const float* Wl    = (const float*)d_in[3];
  const float* bl    = (const float*)d_in[4];
  const float* Wr    = (const float*)d_in[5];
  const float* br    = (const float*)d_in[6];
  const float* We    = (const float*)d_in[7];
  const float* be    = (const float*)d_in[8];
  const float* att   = (const float*)d_in[9];
  // d_in[10] = bias: cancels exactly in BatchNorm mean subtraction -> unused
  const float* gamma = (const float*)d_in[11];
  const float* beta  = (const float*)d_in[12];
  float* out = (float*)d_out;

  char* ws = (char*)d_ws;
  size_t off = 0;
  auto alloc = [&](size_t bytes) {
    size_t o = off;
    off = (off + bytes + 15) & ~size_t(15);
    return o;
  };
  // zero-initialized region first
  const size_t o_deg   = alloc((size_t)(N_NODES + 1) * 4);
  const size_t o_cur   = alloc((size_t)N_NODES * 4);
  const size_t o_cnt   = alloc(16);
  const size_t o_stats = alloc((size_t)8 * 256 * 4);
  const size_t zero_bytes = off;
  // non-zeroed scratch
  const size_t o_offs = alloc((size_t)(N_NODES + 1) * 4);
  const size_t o_ep   = alloc((size_t)N_EDGES * 8);
  const size_t o_wt   = alloc((size_t)256 * 128 * 2);
  const size_t o_xl   = alloc((size_t)N_NODES * HC * 2);
  const size_t o_xr   = alloc((size_t)N_NODES * HC * 2);
  (void)ws_size; (void)in_sizes; (void)n_in; (void)out_size;

  int*   deg    = (int*)(ws + o_deg);
  int*   cur    = (int*)(ws + o_cur);
  int*   cnt    = (int*)(ws + o_cnt);
  float* statsB = (float*)(ws + o_stats);
  int*   offs   = (int*)(ws + o_offs);
  i32x2* epack  = (i32x2*)(ws + o_ep);
  unsigned short* WcatT = (unsigned short*)(ws + o_wt);
  unsigned short* xl    = (unsigned short*)(ws + o_xl);
  unsigned short* xr    = (unsigned short*)(ws + o_xr);

  (void)hipMemsetAsync(ws, 0, zero_bytes, stream);

  k_prep<<<3253, 256, 0, stream>>>(eidx, Wl, Wr, deg, WcatT);
  k_gemm_alloc<<<489, 512, 0, stream>>>(x, WcatT, bl, br, xl, xr, deg, cnt, offs);
  k_scatter<<<3125, 256, 0, stream>>>(eidx, eattr, offs, cur, epack);
  k_attagg<<<12500, 256, 0, stream>>>(offs, deg, epack, xl, xr, We, be, att, out,
                                      statsB);
  k_bn<<<6250, 256, 0, stream>>>(statsB, gamma, beta, out);
}